// Round 6
// baseline (284.057 us; speedup 1.0000x reference)
//
#include <hip/hip_runtime.h>
#include <math.h>

#define NS 4096
#define NC 500
#define NF 256
#define NK 400
#define KC_GEMM 16     // split-K chunks (256 rows each)
#define KC_CS   32     // K chunks for colsum (128 rows each)

#define NB_GEMM (32 * KC_GEMM * 2)        // 1024 blocks
#define NB_CS   (KC_CS * 2)               // 64 blocks
#define NB_QUE  ((NC * NF) / 16)          // 8000 blocks (4 waves x 4 rows each)
#define NB_OTH  (NB_GEMM + NB_CS)         // 1088

// ---------------- kernel 1: fused heavy pass ----------------
// Interleaved job mapping: in each group of 8 consecutive blockIdx values,
// slot 0 is a GEMM/colsum block and slots 1-7 are queue blocks, so every CU
// holds a VALU-bound + HBM-bound mix for the whole kernel (pipe overlap).
__global__ __launch_bounds__(256) void k_heavy(
    const float* __restrict__ Xs, const float* __restrict__ Ys, float* __restrict__ Ps,
    const float* __restrict__ Xt, const float* __restrict__ Yt, float* __restrict__ Pt,
    float* __restrict__ CSs, float* __restrict__ CSt,
    const float* __restrict__ queue, const int* __restrict__ qsize,
    float* __restrict__ qsum) {
  __shared__ float ytile[NS / KC_GEMM][16];     // 16 KB (gemm blocks only)
  const int bid = blockIdx.x;
  const int g = bid >> 3, r = bid & 7;

  if (r == 0 && g < NB_GEMM) {
    // ---- GEMM partials: P[kc][c][f] = sum_{n in chunk} Y[n,c] * X[n,f]
    const int z   = g >> 9;                     // 0:src 1:tgt
    const int rem = g & 511;
    const int kc  = rem >> 5;
    const int c0  = (rem & 31) * 16;
    const float* X = z ? Xt : Xs;
    const float* Y = z ? Yt : Ys;
    float*       P = z ? Pt : Ps;
    const int n0   = kc * (NS / KC_GEMM);
    const int cmax = (NC - c0 < 16) ? (NC - c0) : 16;

    for (int i = threadIdx.x; i < (NS / KC_GEMM) * 16; i += 256) {
      int rr = i >> 4, cc = i & 15;
      ytile[rr][cc] = (cc < cmax) ? Y[(size_t)(n0 + rr) * NC + c0 + cc] : 0.f;
    }
    __syncthreads();

    const int f = threadIdx.x;
    float acc[16];
    #pragma unroll
    for (int j = 0; j < 16; ++j) acc[j] = 0.f;

    #pragma unroll 4
    for (int n = 0; n < NS / KC_GEMM; ++n) {
      float xv = X[(size_t)(n0 + n) * NF + f];
      #pragma unroll
      for (int j = 0; j < 16; ++j) acc[j] = fmaf(ytile[n][j], xv, acc[j]);
    }
    #pragma unroll
    for (int j = 0; j < 16; ++j)
      if (c0 + j < NC) P[((size_t)kc * NC + c0 + j) * NF + f] = acc[j];

  } else if (r == 0 && g < NB_OTH) {
    // ---- column sums: CS[kc][c] = sum_{n in chunk} Y[n,c]
    const int b = g - NB_GEMM;
    const float* Y = (b >> 5) ? Yt : Ys;
    float*      CS = (b >> 5) ? CSt : CSs;
    const int kc = b & 31;
    const int n0 = kc * (NS / KC_CS);
    const int t  = threadIdx.x;
    float s0 = 0.f, s1 = 0.f;
    for (int n = n0; n < n0 + NS / KC_CS; ++n) {
      const float* row = Y + (size_t)n * NC;
      s0 += row[t];
      if (t + 256 < NC) s1 += row[t + 256];
    }
    CS[kc * 512 + t] = s0;
    if (t + 256 < NC) CS[kc * 512 + t + 256] = s1;

  } else {
    // ---- masked queue reduction, tail-skip, 4 rows per wave
    // queue ordinal: bijective over [0, NB_QUE)
    const int qb = (g < NB_OTH) ? (7 * g + r - 1) : (bid - NB_OTH);
    const int widx = threadIdx.x >> 6;
    const int lane = threadIdx.x & 63;
    const int r0   = (qb * 4 + widx) * 4;       // 4 consecutive rows
    const int c    = r0 >> 8;                   // NF = 256; same c for all 4
    const int qs   = qsize[c];
    const int L    = (qs + 3) >> 2;             // float4s needed (<=100)
    const float* base = queue + (size_t)r0 * NK;
    float s0 = 0.f, s1 = 0.f, s2 = 0.f, s3 = 0.f;

    if (lane < L) {
      const int k = 4 * lane;                   // 0..255, k < qs guaranteed
      float4 v0 = *reinterpret_cast<const float4*>(base + 0 * NK + k);
      float4 v1 = *reinterpret_cast<const float4*>(base + 1 * NK + k);
      float4 v2 = *reinterpret_cast<const float4*>(base + 2 * NK + k);
      float4 v3 = *reinterpret_cast<const float4*>(base + 3 * NK + k);
      s0 += v0.x; s1 += v1.x; s2 += v2.x; s3 += v3.x;
      if (k + 1 < qs) { s0 += v0.y; s1 += v1.y; s2 += v2.y; s3 += v3.y; }
      if (k + 2 < qs) { s0 += v0.z; s1 += v1.z; s2 += v2.z; s3 += v3.z; }
      if (k + 3 < qs) { s0 += v0.w; s1 += v1.w; s2 += v2.w; s3 += v3.w; }
    }
    if (lane + 64 < L) {
      const int k = 256 + 4 * lane;             // 256..399
      float4 v0 = *reinterpret_cast<const float4*>(base + 0 * NK + k);
      float4 v1 = *reinterpret_cast<const float4*>(base + 1 * NK + k);
      float4 v2 = *reinterpret_cast<const float4*>(base + 2 * NK + k);
      float4 v3 = *reinterpret_cast<const float4*>(base + 3 * NK + k);
      s0 += v0.x; s1 += v1.x; s2 += v2.x; s3 += v3.x;
      if (k + 1 < qs) { s0 += v0.y; s1 += v1.y; s2 += v2.y; s3 += v3.y; }
      if (k + 2 < qs) { s0 += v0.z; s1 += v1.z; s2 += v2.z; s3 += v3.z; }
      if (k + 3 < qs) { s0 += v0.w; s1 += v1.w; s2 += v2.w; s3 += v3.w; }
    }
    #pragma unroll
    for (int m = 32; m; m >>= 1) {
      s0 += __shfl_xor(s0, m); s1 += __shfl_xor(s1, m);
      s2 += __shfl_xor(s2, m); s3 += __shfl_xor(s3, m);
    }
    if (lane == 0)
      *reinterpret_cast<float4*>(&qsum[r0]) = make_float4(s0, s1, s2, s3);
  }
}

// ---------------- kernel 2: finalize means + intra diagonal ----------------
__global__ __launch_bounds__(256) void k_means(
    const float* __restrict__ qsum, const int* __restrict__ qsize,
    const float* __restrict__ Psrc, const float* __restrict__ Ptgt,
    const float* __restrict__ CSsrc, const float* __restrict__ CStgt,
    float* __restrict__ MS, float* __restrict__ MT, float* __restrict__ ipart) {
  const int c = blockIdx.x, f = threadIdx.x;
  float cs_s = 0.f, cs_t = 0.f;
  #pragma unroll
  for (int kc = 0; kc < KC_CS; ++kc) {
    cs_s += CSsrc[kc * 512 + c];
    cs_t += CStgt[kc * 512 + c];
  }
  float num = (float)qsize[c];
  float ns = qsum[(size_t)c * NF + f];
  float nt = 0.f;
  #pragma unroll
  for (int kc = 0; kc < KC_GEMM; ++kc) {
    ns += Psrc[((size_t)kc * NC + c) * NF + f];
    nt += Ptgt[((size_t)kc * NC + c) * NF + f];
  }
  float ms = ns / (num + cs_s + 1e-8f);
  float mt = nt / (cs_t + 1e-8f);
  MS[(size_t)c * NF + f] = ms;
  MT[(size_t)c * NF + f] = mt;

  float d = ms - mt;
  float s = d * d;
  #pragma unroll
  for (int m = 32; m; m >>= 1) s += __shfl_xor(s, m);
  __shared__ float red[4];
  int wid = f >> 6, lane = f & 63;
  if (lane == 0) red[wid] = s;
  __syncthreads();
  if (f == 0) ipart[c] = sqrtf(fmaxf(red[0] + red[1] + red[2] + red[3], 1e-12f));
}

// ---------------- kernel 3: pairwise distances (16x16 tiles) ----------------
#define TC 16
#define NBT 32                              // ceil(500/16)
__global__ __launch_bounds__(256) void k_dist(const float* __restrict__ MS,
                                              float* __restrict__ epart) {
  __shared__ float a[TC][NF + 4];
  __shared__ float b[TC][NF + 4];
  const int bi = blockIdx.x & (NBT - 1);
  const int bj = blockIdx.x >> 5;

  for (int i = threadIdx.x; i < TC * (NF / 4); i += 256) {
    int rr = i >> 6, fq = (i & 63) * 4;
    int c1 = bi * TC + rr;
    int c2 = bj * TC + rr;
    float4 va = (c1 < NC) ? *reinterpret_cast<const float4*>(&MS[(size_t)c1 * NF + fq])
                          : make_float4(0.f, 0.f, 0.f, 0.f);
    float4 vb = (c2 < NC) ? *reinterpret_cast<const float4*>(&MS[(size_t)c2 * NF + fq])
                          : make_float4(0.f, 0.f, 0.f, 0.f);
    *reinterpret_cast<float4*>(&a[rr][fq]) = va;
    *reinterpret_cast<float4*>(&b[rr][fq]) = vb;
  }
  __syncthreads();

  const int i1 = threadIdx.x >> 4, i2 = threadIdx.x & 15;
  float s = 0.f;
  #pragma unroll 8
  for (int fq = 0; fq < NF; fq += 4) {
    float4 va = *reinterpret_cast<const float4*>(&a[i1][fq]);
    float4 vb = *reinterpret_cast<const float4*>(&b[i2][fq]);
    float d0 = va.x - vb.x, d1 = va.y - vb.y, d2 = va.z - vb.z, d3 = va.w - vb.w;
    s = fmaf(d0, d0, s); s = fmaf(d1, d1, s); s = fmaf(d2, d2, s); s = fmaf(d3, d3, s);
  }
  bool valid = (bi * TC + i1 < NC) && (bj * TC + i2 < NC);
  float rr = valid ? sqrtf(fmaxf(s, 1e-12f)) : 0.f;

  #pragma unroll
  for (int m = 32; m; m >>= 1) rr += __shfl_xor(rr, m);
  __shared__ float red[4];
  int wid = threadIdx.x >> 6, lane = threadIdx.x & 63;
  if (lane == 0) red[wid] = rr;
  __syncthreads();
  if (threadIdx.x == 0) epart[blockIdx.x] = red[0] + red[1] + red[2] + red[3];
}

// ---------------- kernel 4: final scalars ----------------
__global__ __launch_bounds__(1024) void k_final(const float* __restrict__ ipart,
                                                const float* __restrict__ epart,
                                                float* __restrict__ out) {
  const int t = threadIdx.x;                // 1024 threads
  float si = (t < NC) ? ipart[t] : 0.f;
  float se = epart[t];
  #pragma unroll
  for (int m = 32; m; m >>= 1) { si += __shfl_xor(si, m); se += __shfl_xor(se, m); }
  __shared__ float ri[16], re[16];
  int wid = t >> 6, lane = t & 63;
  if (lane == 0) { ri[wid] = si; re[wid] = se; }
  __syncthreads();
  if (t == 0) {
    float A = 0.f, B = 0.f;
    #pragma unroll
    for (int w = 0; w < 16; ++w) { A += ri[w]; B += re[w]; }
    out[0] = A / (float)NC;
    out[1] = B / ((float)NC * (float)NC);
  }
}

extern "C" void kernel_launch(void* const* d_in, const int* in_sizes, int n_in,
                              void* d_out, int out_size, void* d_ws, size_t ws_size,
                              hipStream_t stream) {
  const float* src_x = (const float*)d_in[0];
  const float* tgt_x = (const float*)d_in[1];
  const float* src_y = (const float*)d_in[2];
  const float* tgt_y = (const float*)d_in[3];
  const float* queue = (const float*)d_in[4];
  const int*   qsize = (const int*)d_in[5];
  float* out = (float*)d_out;

  float* ws    = (float*)d_ws;
  float* qsum  = ws;                                   // 128000
  float* Psrc  = qsum + NC * NF;                       // 16 * 128000
  float* Ptgt  = Psrc + (size_t)KC_GEMM * NC * NF;     // 16 * 128000
  float* CSs   = Ptgt + (size_t)KC_GEMM * NC * NF;     // 32 * 512
  float* CSt   = CSs + KC_CS * 512;                    // 32 * 512
  float* MS    = CSt + KC_CS * 512;                    // 128000
  float* MT    = MS + NC * NF;                         // 128000
  float* ipart = MT + NC * NF;                         // 500
  float* epart = ipart + NC;                           // 1024

  // 1) fused heavy pass: gemm + colsum + queue reduction (interleaved jobs)
  k_heavy<<<NB_OTH * 8 + (NB_QUE - NB_OTH * 7), 256, 0, stream>>>(
      src_x, src_y, Psrc, tgt_x, tgt_y, Ptgt, CSs, CSt, queue, qsize, qsum);

  // 2) means + intra diagonal
  k_means<<<NC, 256, 0, stream>>>(qsum, qsize, Psrc, Ptgt, CSs, CSt, MS, MT, ipart);

  // 3) pairwise distances
  k_dist<<<NBT * NBT, 256, 0, stream>>>(MS, epart);

  // 4) final reduction
  k_final<<<1, 1024, 0, stream>>>(ipart, epart, out);
}

// Round 7
// 170.055 us; speedup vs baseline: 1.6704x; 1.6704x over previous
//
#include <hip/hip_runtime.h>
#include <math.h>

#define NS 4096
#define NC 500
#define NF 256
#define NK 400
#define KC_GEMM 16     // split-K chunks (256 rows each)
#define KC_CS   32     // K chunks for colsum (128 rows each)

#define NB_GEMM (32 * KC_GEMM * 2)        // 1024 blocks
#define NB_CS   (KC_CS * 2)               // 64 blocks
#define NB_QUE  ((NC * NF) / 16)          // 8000 blocks (4 waves x 4 rows each)
#define NB_OTH  (NB_GEMM + NB_CS)         // 1088

// ---------------- kernel 1: fused heavy pass ----------------
// Interleaved job mapping with DIAGONAL heavy slot: in group g of 8 blocks,
// the heavy (gemm/colsum) block is at slot r == (g & 7). XCD = bid % 8 on
// MI355X (confirmed R6: slot-0 pinning put all heavy work on XCD 0), so the
// diagonal spreads heavy blocks evenly over all 8 XCDs while every dispatch
// window still mixes 1 VALU-bound block with 7 HBM-bound blocks.
__global__ __launch_bounds__(256) void k_heavy(
    const float* __restrict__ Xs, const float* __restrict__ Ys, float* __restrict__ Ps,
    const float* __restrict__ Xt, const float* __restrict__ Yt, float* __restrict__ Pt,
    float* __restrict__ CSs, float* __restrict__ CSt,
    const float* __restrict__ queue, const int* __restrict__ qsize,
    float* __restrict__ qsum) {
  __shared__ float ytile[NS / KC_GEMM][16];     // 16 KB (gemm blocks only)
  const int bid = blockIdx.x;
  const int g = bid >> 3, r = bid & 7;
  const int hs = g & 7;                         // heavy slot (diagonal)
  const bool heavy = (r == hs) && (g < NB_OTH);

  if (heavy && g < NB_GEMM) {
    // ---- GEMM partials: P[kc][c][f] = sum_{n in chunk} Y[n,c] * X[n,f]
    const int z   = g >> 9;                     // 0:src 1:tgt
    const int rem = g & 511;
    const int kc  = rem >> 5;
    const int c0  = (rem & 31) * 16;
    const float* X = z ? Xt : Xs;
    const float* Y = z ? Yt : Ys;
    float*       P = z ? Pt : Ps;
    const int n0   = kc * (NS / KC_GEMM);
    const int cmax = (NC - c0 < 16) ? (NC - c0) : 16;

    for (int i = threadIdx.x; i < (NS / KC_GEMM) * 16; i += 256) {
      int rr = i >> 4, cc = i & 15;
      ytile[rr][cc] = (cc < cmax) ? Y[(size_t)(n0 + rr) * NC + c0 + cc] : 0.f;
    }
    __syncthreads();

    const int f = threadIdx.x;
    float acc[16];
    #pragma unroll
    for (int j = 0; j < 16; ++j) acc[j] = 0.f;

    #pragma unroll 4
    for (int n = 0; n < NS / KC_GEMM; ++n) {
      float xv = X[(size_t)(n0 + n) * NF + f];
      #pragma unroll
      for (int j = 0; j < 16; ++j) acc[j] = fmaf(ytile[n][j], xv, acc[j]);
    }
    #pragma unroll
    for (int j = 0; j < 16; ++j)
      if (c0 + j < NC) P[((size_t)kc * NC + c0 + j) * NF + f] = acc[j];

  } else if (heavy) {
    // ---- column sums: CS[kc][c] = sum_{n in chunk} Y[n,c]
    const int b = g - NB_GEMM;
    const float* Y = (b >> 5) ? Yt : Ys;
    float*      CS = (b >> 5) ? CSt : CSs;
    const int kc = b & 31;
    const int n0 = kc * (NS / KC_CS);
    const int t  = threadIdx.x;
    float s0 = 0.f, s1 = 0.f;
    for (int n = n0; n < n0 + NS / KC_CS; ++n) {
      const float* row = Y + (size_t)n * NC;
      s0 += row[t];
      if (t + 256 < NC) s1 += row[t + 256];
    }
    CS[kc * 512 + t] = s0;
    if (t + 256 < NC) CS[kc * 512 + t + 256] = s1;

  } else {
    // ---- masked queue reduction, tail-skip, 4 rows per wave
    // queue ordinal: bijective over [0, NB_QUE)
    const int qb = (g < NB_OTH) ? (7 * g + (r < hs ? r : r - 1))
                                : (bid - NB_OTH);
    const int widx = threadIdx.x >> 6;
    const int lane = threadIdx.x & 63;
    const int r0   = (qb * 4 + widx) * 4;       // 4 consecutive rows
    const int c    = r0 >> 8;                   // NF = 256; same c for all 4
    const int qs   = qsize[c];
    const int L    = (qs + 3) >> 2;             // float4s needed (<=100)
    const float* base = queue + (size_t)r0 * NK;
    float s0 = 0.f, s1 = 0.f, s2 = 0.f, s3 = 0.f;

    if (lane < L) {
      const int k = 4 * lane;                   // 0..255, k < qs guaranteed
      float4 v0 = *reinterpret_cast<const float4*>(base + 0 * NK + k);
      float4 v1 = *reinterpret_cast<const float4*>(base + 1 * NK + k);
      float4 v2 = *reinterpret_cast<const float4*>(base + 2 * NK + k);
      float4 v3 = *reinterpret_cast<const float4*>(base + 3 * NK + k);
      s0 += v0.x; s1 += v1.x; s2 += v2.x; s3 += v3.x;
      if (k + 1 < qs) { s0 += v0.y; s1 += v1.y; s2 += v2.y; s3 += v3.y; }
      if (k + 2 < qs) { s0 += v0.z; s1 += v1.z; s2 += v2.z; s3 += v3.z; }
      if (k + 3 < qs) { s0 += v0.w; s1 += v1.w; s2 += v2.w; s3 += v3.w; }
    }
    if (lane + 64 < L) {
      const int k = 256 + 4 * lane;             // 256..399
      float4 v0 = *reinterpret_cast<const float4*>(base + 0 * NK + k);
      float4 v1 = *reinterpret_cast<const float4*>(base + 1 * NK + k);
      float4 v2 = *reinterpret_cast<const float4*>(base + 2 * NK + k);
      float4 v3 = *reinterpret_cast<const float4*>(base + 3 * NK + k);
      s0 += v0.x; s1 += v1.x; s2 += v2.x; s3 += v3.x;
      if (k + 1 < qs) { s0 += v0.y; s1 += v1.y; s2 += v2.y; s3 += v3.y; }
      if (k + 2 < qs) { s0 += v0.z; s1 += v1.z; s2 += v2.z; s3 += v3.z; }
      if (k + 3 < qs) { s0 += v0.w; s1 += v1.w; s2 += v2.w; s3 += v3.w; }
    }
    #pragma unroll
    for (int m = 32; m; m >>= 1) {
      s0 += __shfl_xor(s0, m); s1 += __shfl_xor(s1, m);
      s2 += __shfl_xor(s2, m); s3 += __shfl_xor(s3, m);
    }
    if (lane == 0)
      *reinterpret_cast<float4*>(&qsum[r0]) = make_float4(s0, s1, s2, s3);
  }
}

// ---------------- kernel 2: finalize means + intra diagonal ----------------
__global__ __launch_bounds__(256) void k_means(
    const float* __restrict__ qsum, const int* __restrict__ qsize,
    const float* __restrict__ Psrc, const float* __restrict__ Ptgt,
    const float* __restrict__ CSsrc, const float* __restrict__ CStgt,
    float* __restrict__ MS, float* __restrict__ MT, float* __restrict__ ipart) {
  const int c = blockIdx.x, f = threadIdx.x;
  float cs_s = 0.f, cs_t = 0.f;
  #pragma unroll
  for (int kc = 0; kc < KC_CS; ++kc) {
    cs_s += CSsrc[kc * 512 + c];
    cs_t += CStgt[kc * 512 + c];
  }
  float num = (float)qsize[c];
  float ns = qsum[(size_t)c * NF + f];
  float nt = 0.f;
  #pragma unroll
  for (int kc = 0; kc < KC_GEMM; ++kc) {
    ns += Psrc[((size_t)kc * NC + c) * NF + f];
    nt += Ptgt[((size_t)kc * NC + c) * NF + f];
  }
  float ms = ns / (num + cs_s + 1e-8f);
  float mt = nt / (cs_t + 1e-8f);
  MS[(size_t)c * NF + f] = ms;
  MT[(size_t)c * NF + f] = mt;

  float d = ms - mt;
  float s = d * d;
  #pragma unroll
  for (int m = 32; m; m >>= 1) s += __shfl_xor(s, m);
  __shared__ float red[4];
  int wid = f >> 6, lane = f & 63;
  if (lane == 0) red[wid] = s;
  __syncthreads();
  if (f == 0) ipart[c] = sqrtf(fmaxf(red[0] + red[1] + red[2] + red[3], 1e-12f));
}

// ---------------- kernel 3: pairwise distances (16x16 tiles) ----------------
#define TC 16
#define NBT 32                              // ceil(500/16)
__global__ __launch_bounds__(256) void k_dist(const float* __restrict__ MS,
                                              float* __restrict__ epart) {
  __shared__ float a[TC][NF + 4];
  __shared__ float b[TC][NF + 4];
  const int bi = blockIdx.x & (NBT - 1);
  const int bj = blockIdx.x >> 5;

  for (int i = threadIdx.x; i < TC * (NF / 4); i += 256) {
    int rr = i >> 6, fq = (i & 63) * 4;
    int c1 = bi * TC + rr;
    int c2 = bj * TC + rr;
    float4 va = (c1 < NC) ? *reinterpret_cast<const float4*>(&MS[(size_t)c1 * NF + fq])
                          : make_float4(0.f, 0.f, 0.f, 0.f);
    float4 vb = (c2 < NC) ? *reinterpret_cast<const float4*>(&MS[(size_t)c2 * NF + fq])
                          : make_float4(0.f, 0.f, 0.f, 0.f);
    *reinterpret_cast<float4*>(&a[rr][fq]) = va;
    *reinterpret_cast<float4*>(&b[rr][fq]) = vb;
  }
  __syncthreads();

  const int i1 = threadIdx.x >> 4, i2 = threadIdx.x & 15;
  float s = 0.f;
  #pragma unroll 8
  for (int fq = 0; fq < NF; fq += 4) {
    float4 va = *reinterpret_cast<const float4*>(&a[i1][fq]);
    float4 vb = *reinterpret_cast<const float4*>(&b[i2][fq]);
    float d0 = va.x - vb.x, d1 = va.y - vb.y, d2 = va.z - vb.z, d3 = va.w - vb.w;
    s = fmaf(d0, d0, s); s = fmaf(d1, d1, s); s = fmaf(d2, d2, s); s = fmaf(d3, d3, s);
  }
  bool valid = (bi * TC + i1 < NC) && (bj * TC + i2 < NC);
  float rr = valid ? sqrtf(fmaxf(s, 1e-12f)) : 0.f;

  #pragma unroll
  for (int m = 32; m; m >>= 1) rr += __shfl_xor(rr, m);
  __shared__ float red[4];
  int wid = threadIdx.x >> 6, lane = threadIdx.x & 63;
  if (lane == 0) red[wid] = rr;
  __syncthreads();
  if (threadIdx.x == 0) epart[blockIdx.x] = red[0] + red[1] + red[2] + red[3];
}

// ---------------- kernel 4: final scalars ----------------
__global__ __launch_bounds__(1024) void k_final(const float* __restrict__ ipart,
                                                const float* __restrict__ epart,
                                                float* __restrict__ out) {
  const int t = threadIdx.x;                // 1024 threads
  float si = (t < NC) ? ipart[t] : 0.f;
  float se = epart[t];
  #pragma unroll
  for (int m = 32; m; m >>= 1) { si += __shfl_xor(si, m); se += __shfl_xor(se, m); }
  __shared__ float ri[16], re[16];
  int wid = t >> 6, lane = t & 63;
  if (lane == 0) { ri[wid] = si; re[wid] = se; }
  __syncthreads();
  if (t == 0) {
    float A = 0.f, B = 0.f;
    #pragma unroll
    for (int w = 0; w < 16; ++w) { A += ri[w]; B += re[w]; }
    out[0] = A / (float)NC;
    out[1] = B / ((float)NC * (float)NC);
  }
}

extern "C" void kernel_launch(void* const* d_in, const int* in_sizes, int n_in,
                              void* d_out, int out_size, void* d_ws, size_t ws_size,
                              hipStream_t stream) {
  const float* src_x = (const float*)d_in[0];
  const float* tgt_x = (const float*)d_in[1];
  const float* src_y = (const float*)d_in[2];
  const float* tgt_y = (const float*)d_in[3];
  const float* queue = (const float*)d_in[4];
  const int*   qsize = (const int*)d_in[5];
  float* out = (float*)d_out;

  float* ws    = (float*)d_ws;
  float* qsum  = ws;                                   // 128000
  float* Psrc  = qsum + NC * NF;                       // 16 * 128000
  float* Ptgt  = Psrc + (size_t)KC_GEMM * NC * NF;     // 16 * 128000
  float* CSs   = Ptgt + (size_t)KC_GEMM * NC * NF;     // 32 * 512
  float* CSt   = CSs + KC_CS * 512;                    // 32 * 512
  float* MS    = CSt + KC_CS * 512;                    // 128000
  float* MT    = MS + NC * NF;                         // 128000
  float* ipart = MT + NC * NF;                         // 500
  float* epart = ipart + NC;                           // 1024

  // 1) fused heavy pass: gemm + colsum + queue reduction (diagonal interleave)
  k_heavy<<<NB_OTH * 8 + (NB_QUE - NB_OTH * 7), 256, 0, stream>>>(
      src_x, src_y, Psrc, tgt_x, tgt_y, Ptgt, CSs, CSt, queue, qsize, qsum);

  // 2) means + intra diagonal
  k_means<<<NC, 256, 0, stream>>>(qsum, qsize, Psrc, Ptgt, CSs, CSt, MS, MT, ipart);

  // 3) pairwise distances
  k_dist<<<NBT * NBT, 256, 0, stream>>>(MS, epart);

  // 4) final reduction
  k_final<<<1, 1024, 0, stream>>>(ipart, epart, out);
}

// Round 8
// 75.828 us; speedup vs baseline: 3.7461x; 2.2426x over previous
//
#include <hip/hip_runtime.h>
#include <math.h>

#define NS 4096
#define NC 500
#define NF 256
#define NK 400
#define KC_GEMM 16     // split-K chunks (256 rows each)
#define KC_CS   32     // K chunks for colsum (128 rows each)

#define NB_GEMM (32 * KC_GEMM * 2)        // 1024 blocks
#define NB_CS   (KC_CS * 2)               // 64 blocks
#define NB_OTH  (NB_GEMM + NB_CS)         // 1088
#define NB_QUE  ((NC * NF) / 32)          // 4000 blocks (4 waves x 8 rows each)

// ---------------- kernel 1: fused heavy pass ----------------
// CONTIGUOUS job mapping (R5-measured best): [0,1024) gemm | [1024,1088)
// colsum | [1088,5088) queue. Interleaved mappings (R6/R7) regressed 2-3.5x:
// heavy-block convoys in the per-XCD in-order dispatch window serialize the
// machine. Contiguous heavy-first lets GEMM (VALU) run while queue (HBM)
// streams behind it.
__global__ __launch_bounds__(256) void k_heavy(
    const float* __restrict__ Xs, const float* __restrict__ Ys, float* __restrict__ Ps,
    const float* __restrict__ Xt, const float* __restrict__ Yt, float* __restrict__ Pt,
    float* __restrict__ CSs, float* __restrict__ CSt,
    const float* __restrict__ queue, const int* __restrict__ qsize,
    float* __restrict__ qsum) {
  __shared__ float ytile[NS / KC_GEMM][16];     // 16 KB (gemm blocks only)
  const int bid = blockIdx.x;

  if (bid < NB_GEMM) {
    // ---- GEMM partials: P[kc][c][f] = sum_{n in chunk} Y[n,c] * X[n,f]
    // ytile[n][j] reads are wave-uniform -> LDS broadcast (free)
    const int z   = bid >> 9;                   // 0:src 1:tgt
    const int rem = bid & 511;
    const int kc  = rem >> 5;
    const int c0  = (rem & 31) * 16;
    const float* X = z ? Xt : Xs;
    const float* Y = z ? Yt : Ys;
    float*       P = z ? Pt : Ps;
    const int n0   = kc * (NS / KC_GEMM);
    const int cmax = (NC - c0 < 16) ? (NC - c0) : 16;

    for (int i = threadIdx.x; i < (NS / KC_GEMM) * 16; i += 256) {
      int rr = i >> 4, cc = i & 15;
      ytile[rr][cc] = (cc < cmax) ? Y[(size_t)(n0 + rr) * NC + c0 + cc] : 0.f;
    }
    __syncthreads();

    const int f = threadIdx.x;
    float acc[16];
    #pragma unroll
    for (int j = 0; j < 16; ++j) acc[j] = 0.f;

    #pragma unroll 4
    for (int n = 0; n < NS / KC_GEMM; ++n) {
      float xv = X[(size_t)(n0 + n) * NF + f];
      #pragma unroll
      for (int j = 0; j < 16; ++j) acc[j] = fmaf(ytile[n][j], xv, acc[j]);
    }
    #pragma unroll
    for (int j = 0; j < 16; ++j)
      if (c0 + j < NC) P[((size_t)kc * NC + c0 + j) * NF + f] = acc[j];

  } else if (bid < NB_OTH) {
    // ---- column sums: CS[kc][c] = sum_{n in chunk} Y[n,c]
    const int b = bid - NB_GEMM;
    const float* Y = (b >> 5) ? Yt : Ys;
    float*      CS = (b >> 5) ? CSt : CSs;
    const int kc = b & 31;
    const int n0 = kc * (NS / KC_CS);
    const int t  = threadIdx.x;
    float s0 = 0.f, s1 = 0.f;
    for (int n = n0; n < n0 + NS / KC_CS; ++n) {
      const float* row = Y + (size_t)n * NC;
      s0 += row[t];
      if (t + 256 < NC) s1 += row[t + 256];
    }
    CS[kc * 512 + t] = s0;
    if (t + 256 < NC) CS[kc * 512 + t + 256] = s1;

  } else {
    // ---- masked queue reduction, tail-skip, 8 rows per wave (same class
    //      -> uniform branches; up to 16 independent float4 loads in flight)
    const int qb   = bid - NB_OTH;
    const int widx = threadIdx.x >> 6;
    const int lane = threadIdx.x & 63;
    const int r0   = (qb * 4 + widx) * 8;       // 8 consecutive rows
    const int c    = r0 >> 8;                   // NF = 256; same c for all 8
    const int qs   = qsize[c];
    const int L    = (qs + 3) >> 2;             // float4s needed (<=100)
    const float* base = queue + (size_t)r0 * NK;
    float s0 = 0.f, s1 = 0.f, s2 = 0.f, s3 = 0.f;
    float s4 = 0.f, s5 = 0.f, s6 = 0.f, s7 = 0.f;

    if (lane < L) {
      const int k = 4 * lane;                   // 0..255, k < qs guaranteed
      float4 v0 = *reinterpret_cast<const float4*>(base + 0 * NK + k);
      float4 v1 = *reinterpret_cast<const float4*>(base + 1 * NK + k);
      float4 v2 = *reinterpret_cast<const float4*>(base + 2 * NK + k);
      float4 v3 = *reinterpret_cast<const float4*>(base + 3 * NK + k);
      float4 v4 = *reinterpret_cast<const float4*>(base + 4 * NK + k);
      float4 v5 = *reinterpret_cast<const float4*>(base + 5 * NK + k);
      float4 v6 = *reinterpret_cast<const float4*>(base + 6 * NK + k);
      float4 v7 = *reinterpret_cast<const float4*>(base + 7 * NK + k);
      s0 += v0.x; s1 += v1.x; s2 += v2.x; s3 += v3.x;
      s4 += v4.x; s5 += v5.x; s6 += v6.x; s7 += v7.x;
      if (k + 1 < qs) { s0 += v0.y; s1 += v1.y; s2 += v2.y; s3 += v3.y;
                        s4 += v4.y; s5 += v5.y; s6 += v6.y; s7 += v7.y; }
      if (k + 2 < qs) { s0 += v0.z; s1 += v1.z; s2 += v2.z; s3 += v3.z;
                        s4 += v4.z; s5 += v5.z; s6 += v6.z; s7 += v7.z; }
      if (k + 3 < qs) { s0 += v0.w; s1 += v1.w; s2 += v2.w; s3 += v3.w;
                        s4 += v4.w; s5 += v5.w; s6 += v6.w; s7 += v7.w; }
    }
    if (lane + 64 < L) {
      const int k = 256 + 4 * lane;             // 256..399
      float4 v0 = *reinterpret_cast<const float4*>(base + 0 * NK + k);
      float4 v1 = *reinterpret_cast<const float4*>(base + 1 * NK + k);
      float4 v2 = *reinterpret_cast<const float4*>(base + 2 * NK + k);
      float4 v3 = *reinterpret_cast<const float4*>(base + 3 * NK + k);
      float4 v4 = *reinterpret_cast<const float4*>(base + 4 * NK + k);
      float4 v5 = *reinterpret_cast<const float4*>(base + 5 * NK + k);
      float4 v6 = *reinterpret_cast<const float4*>(base + 6 * NK + k);
      float4 v7 = *reinterpret_cast<const float4*>(base + 7 * NK + k);
      s0 += v0.x; s1 += v1.x; s2 += v2.x; s3 += v3.x;
      s4 += v4.x; s5 += v5.x; s6 += v6.x; s7 += v7.x;
      if (k + 1 < qs) { s0 += v0.y; s1 += v1.y; s2 += v2.y; s3 += v3.y;
                        s4 += v4.y; s5 += v5.y; s6 += v6.y; s7 += v7.y; }
      if (k + 2 < qs) { s0 += v0.z; s1 += v1.z; s2 += v2.z; s3 += v3.z;
                        s4 += v4.z; s5 += v5.z; s6 += v6.z; s7 += v7.z; }
      if (k + 3 < qs) { s0 += v0.w; s1 += v1.w; s2 += v2.w; s3 += v3.w;
                        s4 += v4.w; s5 += v5.w; s6 += v6.w; s7 += v7.w; }
    }
    #pragma unroll
    for (int m = 32; m; m >>= 1) {
      s0 += __shfl_xor(s0, m); s1 += __shfl_xor(s1, m);
      s2 += __shfl_xor(s2, m); s3 += __shfl_xor(s3, m);
      s4 += __shfl_xor(s4, m); s5 += __shfl_xor(s5, m);
      s6 += __shfl_xor(s6, m); s7 += __shfl_xor(s7, m);
    }
    if (lane == 0) {
      *reinterpret_cast<float4*>(&qsum[r0])     = make_float4(s0, s1, s2, s3);
      *reinterpret_cast<float4*>(&qsum[r0 + 4]) = make_float4(s4, s5, s6, s7);
    }
  }
}

// ---------------- kernel 2: finalize means + intra diagonal ----------------
// wave per class (4 classes/block), float4 per lane over features
__global__ __launch_bounds__(256) void k_means(
    const float* __restrict__ qsum, const int* __restrict__ qsize,
    const float* __restrict__ Psrc, const float* __restrict__ Ptgt,
    const float* __restrict__ CSsrc, const float* __restrict__ CStgt,
    float* __restrict__ MS, float* __restrict__ MT, float* __restrict__ ipart) {
  const int c = blockIdx.x * 4 + (threadIdx.x >> 6);
  const int lane = threadIdx.x & 63;
  const int f4 = lane * 4;                     // features f4..f4+3
  if (c >= NC) return;

  float cs_s = 0.f, cs_t = 0.f;
  #pragma unroll
  for (int kc = 0; kc < KC_CS; ++kc) {
    cs_s += CSsrc[kc * 512 + c];
    cs_t += CStgt[kc * 512 + c];
  }
  float num = (float)qsize[c];
  float4 ns = *reinterpret_cast<const float4*>(&qsum[(size_t)c * NF + f4]);
  float4 nt = make_float4(0.f, 0.f, 0.f, 0.f);
  #pragma unroll
  for (int kc = 0; kc < KC_GEMM; ++kc) {
    float4 ps = *reinterpret_cast<const float4*>(&Psrc[((size_t)kc * NC + c) * NF + f4]);
    float4 pt = *reinterpret_cast<const float4*>(&Ptgt[((size_t)kc * NC + c) * NF + f4]);
    ns.x += ps.x; ns.y += ps.y; ns.z += ps.z; ns.w += ps.w;
    nt.x += pt.x; nt.y += pt.y; nt.z += pt.z; nt.w += pt.w;
  }
  float rs = 1.f / (num + cs_s + 1e-8f);
  float rt = 1.f / (cs_t + 1e-8f);
  float4 ms = make_float4(ns.x * rs, ns.y * rs, ns.z * rs, ns.w * rs);
  float4 mt = make_float4(nt.x * rt, nt.y * rt, nt.z * rt, nt.w * rt);
  *reinterpret_cast<float4*>(&MS[(size_t)c * NF + f4]) = ms;
  *reinterpret_cast<float4*>(&MT[(size_t)c * NF + f4]) = mt;

  float dx = ms.x - mt.x, dy = ms.y - mt.y, dz = ms.z - mt.z, dw = ms.w - mt.w;
  float s = dx * dx + dy * dy + dz * dz + dw * dw;
  #pragma unroll
  for (int m = 32; m; m >>= 1) s += __shfl_xor(s, m);
  if (lane == 0) ipart[c] = sqrtf(fmaxf(s, 1e-12f));
}

// ---------------- kernel 3: pairwise distances (16x16 tiles) ----------------
#define TC 16
#define NBT 32                              // ceil(500/16)
__global__ __launch_bounds__(256) void k_dist(const float* __restrict__ MS,
                                              float* __restrict__ epart) {
  __shared__ float a[TC][NF + 4];
  __shared__ float b[TC][NF + 4];
  const int bi = blockIdx.x & (NBT - 1);
  const int bj = blockIdx.x >> 5;

  for (int i = threadIdx.x; i < TC * (NF / 4); i += 256) {
    int rr = i >> 6, fq = (i & 63) * 4;
    int c1 = bi * TC + rr;
    int c2 = bj * TC + rr;
    float4 va = (c1 < NC) ? *reinterpret_cast<const float4*>(&MS[(size_t)c1 * NF + fq])
                          : make_float4(0.f, 0.f, 0.f, 0.f);
    float4 vb = (c2 < NC) ? *reinterpret_cast<const float4*>(&MS[(size_t)c2 * NF + fq])
                          : make_float4(0.f, 0.f, 0.f, 0.f);
    *reinterpret_cast<float4*>(&a[rr][fq]) = va;
    *reinterpret_cast<float4*>(&b[rr][fq]) = vb;
  }
  __syncthreads();

  const int i1 = threadIdx.x >> 4, i2 = threadIdx.x & 15;
  float s = 0.f;
  #pragma unroll 8
  for (int fq = 0; fq < NF; fq += 4) {
    float4 va = *reinterpret_cast<const float4*>(&a[i1][fq]);
    float4 vb = *reinterpret_cast<const float4*>(&b[i2][fq]);
    float d0 = va.x - vb.x, d1 = va.y - vb.y, d2 = va.z - vb.z, d3 = va.w - vb.w;
    s = fmaf(d0, d0, s); s = fmaf(d1, d1, s); s = fmaf(d2, d2, s); s = fmaf(d3, d3, s);
  }
  bool valid = (bi * TC + i1 < NC) && (bj * TC + i2 < NC);
  float rr = valid ? sqrtf(fmaxf(s, 1e-12f)) : 0.f;

  #pragma unroll
  for (int m = 32; m; m >>= 1) rr += __shfl_xor(rr, m);
  __shared__ float red[4];
  int wid = threadIdx.x >> 6, lane = threadIdx.x & 63;
  if (lane == 0) red[wid] = rr;
  __syncthreads();
  if (threadIdx.x == 0) epart[blockIdx.x] = red[0] + red[1] + red[2] + red[3];
}

// ---------------- kernel 4: final scalars ----------------
__global__ __launch_bounds__(1024) void k_final(const float* __restrict__ ipart,
                                                const float* __restrict__ epart,
                                                float* __restrict__ out) {
  const int t = threadIdx.x;                // 1024 threads
  float si = (t < NC) ? ipart[t] : 0.f;
  float se = epart[t];
  #pragma unroll
  for (int m = 32; m; m >>= 1) { si += __shfl_xor(si, m); se += __shfl_xor(se, m); }
  __shared__ float ri[16], re[16];
  int wid = t >> 6, lane = t & 63;
  if (lane == 0) { ri[wid] = si; re[wid] = se; }
  __syncthreads();
  if (t == 0) {
    float A = 0.f, B = 0.f;
    #pragma unroll
    for (int w = 0; w < 16; ++w) { A += ri[w]; B += re[w]; }
    out[0] = A / (float)NC;
    out[1] = B / ((float)NC * (float)NC);
  }
}

extern "C" void kernel_launch(void* const* d_in, const int* in_sizes, int n_in,
                              void* d_out, int out_size, void* d_ws, size_t ws_size,
                              hipStream_t stream) {
  const float* src_x = (const float*)d_in[0];
  const float* tgt_x = (const float*)d_in[1];
  const float* src_y = (const float*)d_in[2];
  const float* tgt_y = (const float*)d_in[3];
  const float* queue = (const float*)d_in[4];
  const int*   qsize = (const int*)d_in[5];
  float* out = (float*)d_out;

  float* ws    = (float*)d_ws;
  float* qsum  = ws;                                   // 128000
  float* Psrc  = qsum + NC * NF;                       // 16 * 128000
  float* Ptgt  = Psrc + (size_t)KC_GEMM * NC * NF;     // 16 * 128000
  float* CSs   = Ptgt + (size_t)KC_GEMM * NC * NF;     // 32 * 512
  float* CSt   = CSs + KC_CS * 512;                    // 32 * 512
  float* MS    = CSt + KC_CS * 512;                    // 128000
  float* MT    = MS + NC * NF;                         // 128000
  float* ipart = MT + NC * NF;                         // 500
  float* epart = ipart + NC;                           // 1024

  // 1) fused heavy pass: gemm + colsum + queue reduction (contiguous jobs)
  k_heavy<<<NB_OTH + NB_QUE, 256, 0, stream>>>(
      src_x, src_y, Psrc, tgt_x, tgt_y, Ptgt, CSs, CSt, queue, qsize, qsum);

  // 2) means + intra diagonal (wave per class)
  k_means<<<(NC + 3) / 4, 256, 0, stream>>>(qsum, qsize, Psrc, Ptgt, CSs, CSt, MS, MT, ipart);

  // 3) pairwise distances
  k_dist<<<NBT * NBT, 256, 0, stream>>>(MS, epart);

  // 4) final reduction
  k_final<<<1, 1024, 0, stream>>>(ipart, epart, out);
}